// Round 1
// baseline (1199.242 us; speedup 1.0000x reference)
//
#include <hip/hip_runtime.h>
#include <cstdint>
#include <cstddef>

#define HH 2048
#define WW 2048
#define NPIX (HH * WW)
#define EPS_NMS 1e-5f
#define EPS_DIV 1e-8f
#define SORT_N 8192
#define SEL_CAP 4096

// ---- workspace layout (bytes) ----
// [0, 64)           : uint32 cnt[16]   cnt[0]=n_cand cnt[1]=n_gt cnt[2]=n_tie cnt[3]=T32 cnt[4]=need_ties
// [64, 32832)       : tie    uint64[4096]
// [32832, 65600)    : sel    uint64[4096]
// [65600, 98368)    : sorted uint64[4096]
// [98368, ...)      : candidates uint64[cap]

__global__ __launch_bounds__(256) void nms_map_kernel(
    const float* __restrict__ low, const float* __restrict__ cur,
    const float* __restrict__ high, const float* __restrict__ oct,
    float* __restrict__ oct_out, unsigned long long* __restrict__ cand,
    unsigned int* __restrict__ cnt, unsigned int cap)
{
    int x = blockIdx.x * blockDim.x + threadIdx.x;
    int y = blockIdx.y;
    if (x >= WW) return;
    int idx = y * WW + x;

    float c = cur[idx];
    float m = -3.402823466e+38f;
    #pragma unroll
    for (int dy = -1; dy <= 1; ++dy) {
        int yy = y + dy;
        if (yy < 0 || yy >= HH) continue;
        int rb = yy * WW;
        #pragma unroll
        for (int dx = -1; dx <= 1; ++dx) {
            int xx = x + dx;
            if (xx < 0 || xx >= WW) continue;
            int j = rb + xx;
            float a = low[j], b = cur[j], d = high[j];
            m = fmaxf(m, fmaxf(a, fmaxf(b, d)));
        }
    }
    float o = oct[idx];
    bool keep = (c - m + EPS_NMS) > 0.0f;                       // strict >, same order as ref
    bool interior = (x > 0) && (y > 0) && (x < WW - 1) && (y < HH - 1);
    float nm = (keep && interior) ? c * (1.0f - o) : 0.0f;
    float ov = o + nm;
    oct_out[idx] = (float)((unsigned char)ov);                  // uint8 truncation, stored as f32

    if (nm > 0.0f) {
        unsigned int fb = __float_as_uint(nm);                  // positive float: bits monotonic
        unsigned int p = atomicAdd(cnt, 1u);
        if (p < cap)
            cand[p] = (((unsigned long long)fb) << 32) | (unsigned int)(~idx);
    }
}

// single-block radix select: find bits of the K-th largest candidate value
__global__ __launch_bounds__(1024) void radix_select_kernel(
    const unsigned long long* __restrict__ cand, unsigned int* cnt,
    unsigned int cap, int K)
{
    __shared__ unsigned int hist[256];
    __shared__ unsigned int sh_prefix, sh_remk;
    int tid = threadIdx.x, bs = blockDim.x;
    unsigned int n = cnt[0]; if (n > cap) n = cap;
    if (tid == 0) { sh_prefix = 0u; sh_remk = (unsigned int)K; }
    __syncthreads();

    for (int shift = 24; shift >= 0; shift -= 8) {
        for (int i = tid; i < 256; i += bs) hist[i] = 0u;
        __syncthreads();
        unsigned int prefix = sh_prefix;
        for (unsigned int i = tid; i < n; i += bs) {
            unsigned int k32 = (unsigned int)(cand[i] >> 32);
            unsigned int hi = (shift == 24) ? 0u : (k32 >> (shift + 8));
            if (hi == prefix) atomicAdd(&hist[(k32 >> shift) & 255u], 1u);
        }
        __syncthreads();
        if (tid == 0) {
            unsigned int cum = 0; int v = 255;
            for (; v >= 0; --v) {
                unsigned int h = hist[v];
                if (cum + h >= sh_remk) {
                    sh_remk -= cum;
                    sh_prefix = (prefix << 8) | (unsigned int)v;
                    break;
                }
                cum += h;
            }
            if (v < 0) sh_prefix = prefix << 8;   // degenerate: fewer than K candidates
        }
        __syncthreads();
    }
    if (tid == 0) { cnt[3] = sh_prefix; cnt[4] = sh_remk; }
}

__global__ __launch_bounds__(256) void compact_kernel(
    const unsigned long long* __restrict__ cand,
    unsigned long long* __restrict__ sel, unsigned long long* __restrict__ tie,
    unsigned int* cnt, unsigned int cap)
{
    unsigned int n = cnt[0]; if (n > cap) n = cap;
    unsigned int T = cnt[3];
    unsigned int stride = gridDim.x * blockDim.x;
    for (unsigned int i = blockIdx.x * blockDim.x + threadIdx.x; i < n; i += stride) {
        unsigned long long key = cand[i];
        unsigned int k32 = (unsigned int)(key >> 32);
        if (k32 > T) {
            unsigned int p = atomicAdd(&cnt[1], 1u);
            if (p < SEL_CAP) sel[p] = key;
        } else if (k32 == T) {
            unsigned int p = atomicAdd(&cnt[2], 1u);
            if (p < SEL_CAP) tie[p] = key;
        }
    }
}

// single-block bitonic sort of (>T candidates + ties), descending by (value, then index asc)
__global__ __launch_bounds__(1024) void sort_topk_kernel(
    const unsigned long long* __restrict__ sel, const unsigned long long* __restrict__ tie,
    unsigned long long* __restrict__ sorted, const unsigned int* cnt, int K)
{
    __shared__ unsigned long long s[SORT_N];
    int tid = threadIdx.x, bs = blockDim.x;
    unsigned int n_gt = cnt[1]; if (n_gt > SEL_CAP) n_gt = SEL_CAP;
    unsigned int n_tie = cnt[2]; if (n_tie > SEL_CAP) n_tie = SEL_CAP;
    unsigned int take_tie = n_tie;
    if (n_gt + take_tie > SORT_N) take_tie = SORT_N - n_gt;
    unsigned int total = n_gt + take_tie;

    for (int i = tid; i < SORT_N; i += bs) {
        unsigned long long v = 0ull;
        if (i < (int)n_gt) v = sel[i];
        else if (i < (int)total) v = tie[i - n_gt];
        s[i] = v;
    }
    __syncthreads();

    for (int k2 = 2; k2 <= SORT_N; k2 <<= 1) {
        for (int j = k2 >> 1; j > 0; j >>= 1) {
            for (int i = tid; i < SORT_N; i += bs) {
                int ixj = i ^ j;
                if (ixj > i) {
                    unsigned long long a = s[i], b = s[ixj];
                    bool up = (i & k2) != 0;           // (i&k2)==0 segments sort descending
                    bool sw = up ? (a > b) : (a < b);
                    if (sw) { s[i] = b; s[ixj] = a; }
                }
            }
            __syncthreads();
        }
    }
    for (int i = tid; i < K; i += bs) sorted[i] = s[i];
}

__global__ __launch_bounds__(256) void finalize_kernel(
    const unsigned long long* __restrict__ sorted,
    const float* __restrict__ low, const float* __restrict__ cur,
    const float* __restrict__ high, const float* __restrict__ aff,
    float* __restrict__ out, int K)
{
    int i = blockIdx.x * blockDim.x + threadIdx.x;
    if (i >= K) return;
    unsigned long long key = sorted[i];
    float val = __uint_as_float((unsigned int)(key >> 32));
    unsigned int idx = ~((unsigned int)key);
    out[i] = val;
    float* laf = out + K + (size_t)i * 6;
    if (idx >= (unsigned int)NPIX) {
        for (int j = 0; j < 6; ++j) laf[j] = 0.0f;
        return;
    }
    int y = (int)(idx >> 11), x = (int)(idx & (WW - 1));
    const float cc[3] = {-0.5f, 0.5f, 1.5f};
    float den = 0.0f, nz = 0.0f, ny = 0.0f, nx = 0.0f;
    #pragma unroll
    for (int dy = -1; dy <= 1; ++dy) {
        int yy = y + dy;
        if (yy < 0 || yy >= HH) continue;
        #pragma unroll
        for (int dx = -1; dx <= 1; ++dx) {
            int xx = x + dx;
            if (xx < 0 || xx >= WW) continue;
            int j = yy * WW + xx;
            float v0 = low[j], v1 = cur[j], v2 = high[j];
            float ssum = v0 + v1 + v2;
            den += ssum;
            nz += -0.5f * v0 + 0.5f * v1 + 1.5f * v2;
            ny += cc[dy + 1] * ssum;
            nx += cc[dx + 1] * ssum;
        }
    }
    float inv = 1.0f / (den + EPS_DIV);
    float s_n = (nz * inv) * (1.0f / 2048.0f);
    float y_n = (ny * inv + (float)y) * (1.0f / 2048.0f);
    float x_n = (nx * inv + (float)x) * (1.0f / 2048.0f);
    float a0 = aff[idx], a1 = aff[NPIX + idx], a2 = aff[2 * NPIX + idx], a3 = aff[3 * NPIX + idx];
    laf[0] = s_n * a0; laf[1] = s_n * a1; laf[2] = x_n;
    laf[3] = s_n * a2; laf[4] = s_n * a3; laf[5] = y_n;
}

extern "C" void kernel_launch(void* const* d_in, const int* in_sizes, int n_in,
                              void* d_out, int out_size, void* d_ws, size_t ws_size,
                              hipStream_t stream) {
    const float* low  = (const float*)d_in[0];
    const float* cur  = (const float*)d_in[1];
    const float* high = (const float*)d_in[2];
    const float* aff  = (const float*)d_in[3];
    const float* oct  = (const float*)d_in[4];
    // (d_in[5] = num_features; K derived from out_size instead)
    int K = (out_size - NPIX) / 7;   // 4096 for this problem
    float* out = (float*)d_out;

    char* ws = (char*)d_ws;
    unsigned int* cnt            = (unsigned int*)ws;
    unsigned long long* tie      = (unsigned long long*)(ws + 64);
    unsigned long long* sel      = (unsigned long long*)(ws + 64 + 32768);
    unsigned long long* sorted   = (unsigned long long*)(ws + 64 + 65536);
    const size_t cand_off = 98368;
    unsigned long long* cand     = (unsigned long long*)(ws + cand_off);
    size_t cap_sz = ws_size > cand_off ? (ws_size - cand_off) / 8 : 0;
    if (cap_sz > (size_t)NPIX) cap_sz = (size_t)NPIX;
    unsigned int cap = (unsigned int)cap_sz;

    hipMemsetAsync(ws, 0, 64, stream);

    dim3 b1(256, 1, 1), g1(WW / 256, HH, 1);
    nms_map_kernel<<<g1, b1, 0, stream>>>(low, cur, high, oct, out + (size_t)7 * K, cand, cnt, cap);
    radix_select_kernel<<<1, 1024, 0, stream>>>(cand, cnt, cap, K);
    compact_kernel<<<512, 256, 0, stream>>>(cand, sel, tie, cnt, cap);
    sort_topk_kernel<<<1, 1024, 0, stream>>>(sel, tie, sorted, cnt, K);
    finalize_kernel<<<(K + 255) / 256, 256, 0, stream>>>(sorted, low, cur, high, aff, out, K);
}

// Round 2
// 368.012 us; speedup vs baseline: 3.2587x; 3.2587x over previous
//
#include <hip/hip_runtime.h>
#include <cstdint>
#include <cstddef>

#define HH 2048
#define WW 2048
#define NPIX (HH * WW)
#define EPS_NMS 1e-5f
#define EPS_DIV 1e-8f
#define NEG_INF (-3.402823466e+38f)
#define ROWS 16         // rows per block in nms kernel
#define LCAP 4096       // per-block LDS candidate capacity
#define SG_CAP 8192     // max selected (>=T) keys

typedef unsigned long long u64;

// ---- workspace layout (bytes) ----
// [0,    64)   : uint32 cnt[16]  cnt[0]=n_cand cnt[1]=n_sel cnt[3]=prefix/T cnt[4]=remk
// [64,  1088)  : uint32 hist[256]
// [4096,69632) : SG u64[8192]  (all keys >= T, unsorted)
// [69632, ...) : candidates u64[cap]

__device__ __forceinline__ float zmax3(const float* __restrict__ low, const float* __restrict__ cur,
                                       const float* __restrict__ high, int j, float& c)
{
    float l = low[j], cc = cur[j], h = high[j];
    c = cc;
    return fmaxf(l, fmaxf(cc, h));
}

// Each block: 256 columns x ROWS rows. Rolling 3-row window of horizontal maxes
// via LDS halo row. ONE global atomic per block for candidate flush.
__global__ __launch_bounds__(256) void nms_map_kernel(
    const float* __restrict__ low, const float* __restrict__ cur,
    const float* __restrict__ high, const float* __restrict__ oct,
    float* __restrict__ oct_out, u64* __restrict__ cand,
    unsigned int* __restrict__ cnt, unsigned int cap)
{
    __shared__ float zbuf[2][258];
    __shared__ unsigned int lcount, lbase;
    __shared__ u64 lcand[LCAP];

    const int tid = threadIdx.x;
    const int x = blockIdx.x * 256 + tid;
    const int y0 = blockIdx.y * ROWS;
    if (tid == 0) lcount = 0u;

    float r0 = NEG_INF, r1 = NEG_INF, r2, c1v = 0.0f, c2v;

    // row processor: compute horizontal 3-max of column z-maxes for row t
    #define DO_ROW(t, rz, cz) {                                                   \
        float* Z = zbuf[((unsigned)((t) + 2)) & 1u];                              \
        float cv = 0.0f, dummy;                                                   \
        int valid = ((t) >= 0) && ((t) < HH);                                     \
        if (valid) {                                                              \
            int jj = (t) * WW + x;                                                \
            Z[tid + 1] = zmax3(low, cur, high, jj, cv);                           \
            if (tid == 0)                                                         \
                Z[0]   = (blockIdx.x == 0) ? NEG_INF                              \
                         : zmax3(low, cur, high, jj - 1, dummy);                  \
            if (tid == 255)                                                       \
                Z[257] = (blockIdx.x == gridDim.x - 1) ? NEG_INF                  \
                         : zmax3(low, cur, high, jj + 1, dummy);                  \
        }                                                                         \
        __syncthreads();                                                          \
        rz = valid ? fmaxf(Z[tid], fmaxf(Z[tid + 1], Z[tid + 2])) : NEG_INF;      \
        cz = cv;                                                                  \
    }

    float cdum;
    DO_ROW(y0 - 1, r0, cdum)
    DO_ROW(y0,     r1, c1v)

    for (int j = 0; j < ROWS; ++j) {
        int y = y0 + j;
        DO_ROW(y + 1, r2, c2v)
        int idx = y * WW + x;
        float o = oct[idx];
        float m = fmaxf(r0, fmaxf(r1, r2));
        bool interior = (x > 0) && (x < WW - 1) && (y > 0) && (y < HH - 1);
        float nm = (((c1v - m + EPS_NMS) > 0.0f) && interior) ? c1v * (1.0f - o) : 0.0f;
        oct_out[idx] = (float)((unsigned char)(o + nm));
        if (nm > 0.0f) {
            unsigned int p = atomicAdd(&lcount, 1u);
            if (p < LCAP)
                lcand[p] = (((u64)__float_as_uint(nm)) << 32) | (unsigned int)(~idx);
        }
        r0 = r1; r1 = r2; c1v = c2v;
    }
    #undef DO_ROW

    __syncthreads();
    unsigned int c = lcount < LCAP ? lcount : LCAP;
    if (tid == 0) lbase = atomicAdd(cnt, c);
    __syncthreads();
    unsigned int base = lbase;
    for (unsigned int i = tid; i < c; i += 256) {
        unsigned int p = base + i;
        if (p < cap) cand[p] = lcand[i];
    }
}

// one 8-bit radix pass: per-block LDS hist -> global hist (gated by current prefix)
__global__ __launch_bounds__(256) void hist_kernel(
    const u64* __restrict__ cand, const unsigned int* __restrict__ cnt,
    unsigned int* __restrict__ hist, unsigned int cap, int pass)
{
    __shared__ unsigned int h[256];
    int tid = threadIdx.x;
    h[tid] = 0u;
    __syncthreads();
    unsigned int n = cnt[0]; if (n > cap) n = cap;
    unsigned int prefix = cnt[3];
    int shift = 24 - 8 * pass;
    unsigned int stride = gridDim.x * blockDim.x;
    for (unsigned int i = blockIdx.x * blockDim.x + tid; i < n; i += stride) {
        unsigned int k32 = (unsigned int)(cand[i] >> 32);
        bool ok = (pass == 0) || ((k32 >> (shift + 8)) == prefix);
        if (ok) atomicAdd(&h[(k32 >> shift) & 255u], 1u);
    }
    __syncthreads();
    if (h[tid]) atomicAdd(&hist[tid], h[tid]);
}

// parallel suffix-scan over 256 bins; update prefix/remk; zero hist for next pass
__global__ __launch_bounds__(256) void pick_kernel(
    unsigned int* __restrict__ cnt, unsigned int* __restrict__ hist, int pass, int K)
{
    __shared__ unsigned int s[256];
    int tid = threadIdx.x;
    unsigned int h = hist[tid];
    s[tid] = h;
    __syncthreads();
    for (int off = 1; off < 256; off <<= 1) {
        unsigned int v = (tid + off < 256) ? s[tid + off] : 0u;
        __syncthreads();
        s[tid] += v;
        __syncthreads();
    }
    unsigned int remk   = (pass == 0) ? (unsigned int)K : cnt[4];
    unsigned int prefix = (pass == 0) ? 0u : cnt[3];
    unsigned int incl = s[tid];
    unsigned int excl = incl - h;
    unsigned int total = s[0];
    __syncthreads();
    if (incl >= remk && excl < remk) {        // unique bin (requires h>0)
        cnt[3] = (prefix << 8) | (unsigned int)tid;
        cnt[4] = remk - excl;
    }
    if (tid == 0 && total < remk)             // degenerate: fewer than K candidates
        cnt[3] = prefix << 8;
    hist[tid] = 0u;
}

// compact all keys with k32 >= T into SG (one global atomic per block)
__global__ __launch_bounds__(256) void compact_kernel(
    const u64* __restrict__ cand, u64* __restrict__ SG,
    unsigned int* __restrict__ cnt, unsigned int cap)
{
    __shared__ unsigned int lc, lb;
    __shared__ u64 buf[2048];
    int tid = threadIdx.x;
    unsigned int n = cnt[0]; if (n > cap) n = cap;
    unsigned int T = cnt[3];
    if (tid == 0) lc = 0u;
    __syncthreads();
    unsigned int stride = gridDim.x * blockDim.x;
    for (unsigned int i = blockIdx.x * blockDim.x + tid; i < n; i += stride) {
        u64 key = cand[i];
        if ((unsigned int)(key >> 32) >= T) {
            unsigned int p = atomicAdd(&lc, 1u);
            if (p < 2048u) buf[p] = key;
        }
    }
    __syncthreads();
    unsigned int c = lc < 2048u ? lc : 2048u;
    if (tid == 0) lb = atomicAdd(&cnt[1], c);
    __syncthreads();
    unsigned int base = lb;
    for (unsigned int i = tid; i < c; i += 256) {
        unsigned int p = base + i;
        if (p < SG_CAP) SG[p] = buf[i];
    }
}

// rank-by-count (exact, unique 64-bit keys) + fused finalize
__global__ __launch_bounds__(256) void rank_finalize_kernel(
    const u64* __restrict__ SG, const unsigned int* __restrict__ cnt,
    const float* __restrict__ low, const float* __restrict__ cur,
    const float* __restrict__ high, const float* __restrict__ aff,
    float* __restrict__ out, int K)
{
    unsigned int m = cnt[1]; if (m > SG_CAP) m = SG_CAP;
    unsigned int e = blockIdx.x * 256 + threadIdx.x;
    if (e >= m) return;
    u64 my = SG[e];
    unsigned int rank = 0, j = 0;
    for (; j + 8 <= m; j += 8) {          // uniform indices -> scalar loads
        rank += (unsigned)(SG[j]     > my) + (unsigned)(SG[j + 1] > my)
              + (unsigned)(SG[j + 2] > my) + (unsigned)(SG[j + 3] > my)
              + (unsigned)(SG[j + 4] > my) + (unsigned)(SG[j + 5] > my)
              + (unsigned)(SG[j + 6] > my) + (unsigned)(SG[j + 7] > my);
    }
    for (; j < m; ++j) rank += (unsigned)(SG[j] > my);
    if (rank >= (unsigned int)K) return;

    float val = __uint_as_float((unsigned int)(my >> 32));
    unsigned int idx = ~((unsigned int)my);
    out[rank] = val;
    float* laf = out + K + (size_t)rank * 6;
    int y = (int)(idx >> 11), x = (int)(idx & (WW - 1));
    const float ccw[3] = {-0.5f, 0.5f, 1.5f};
    float den = 0.0f, nz = 0.0f, ny = 0.0f, nx = 0.0f;
    #pragma unroll
    for (int dy = -1; dy <= 1; ++dy) {
        int yy = y + dy;
        if (yy < 0 || yy >= HH) continue;
        #pragma unroll
        for (int dx = -1; dx <= 1; ++dx) {
            int xx = x + dx;
            if (xx < 0 || xx >= WW) continue;
            int jj = yy * WW + xx;
            float v0 = low[jj], v1 = cur[jj], v2 = high[jj];
            float ssum = v0 + v1 + v2;
            den += ssum;
            nz += -0.5f * v0 + 0.5f * v1 + 1.5f * v2;
            ny += ccw[dy + 1] * ssum;
            nx += ccw[dx + 1] * ssum;
        }
    }
    float inv = 1.0f / (den + EPS_DIV);
    float s_n = (nz * inv) * (1.0f / 2048.0f);
    float y_n = (ny * inv + (float)y) * (1.0f / 2048.0f);
    float x_n = (nx * inv + (float)x) * (1.0f / 2048.0f);
    float a0 = aff[idx], a1 = aff[NPIX + idx], a2 = aff[2 * NPIX + idx], a3 = aff[3 * NPIX + idx];
    laf[0] = s_n * a0; laf[1] = s_n * a1; laf[2] = x_n;
    laf[3] = s_n * a2; laf[4] = s_n * a3; laf[5] = y_n;
}

extern "C" void kernel_launch(void* const* d_in, const int* in_sizes, int n_in,
                              void* d_out, int out_size, void* d_ws, size_t ws_size,
                              hipStream_t stream) {
    const float* low  = (const float*)d_in[0];
    const float* cur  = (const float*)d_in[1];
    const float* high = (const float*)d_in[2];
    const float* aff  = (const float*)d_in[3];
    const float* oct  = (const float*)d_in[4];
    int K = (out_size - NPIX) / 7;   // 4096
    float* out = (float*)d_out;

    char* ws = (char*)d_ws;
    unsigned int* cnt  = (unsigned int*)ws;
    unsigned int* hist = (unsigned int*)(ws + 64);
    u64* SG            = (u64*)(ws + 4096);
    const size_t cand_off = 69632;
    u64* cand          = (u64*)(ws + cand_off);
    size_t cap_sz = ws_size > cand_off ? (ws_size - cand_off) / 8 : 0;
    if (cap_sz > (size_t)NPIX) cap_sz = (size_t)NPIX;
    unsigned int cap = (unsigned int)cap_sz;

    hipMemsetAsync(ws, 0, 1088, stream);                       // cnt + hist
    hipMemsetAsync(out, 0, (size_t)7 * K * sizeof(float), stream);  // vals+lafs safety

    dim3 gb(WW / 256, HH / ROWS, 1);
    nms_map_kernel<<<gb, 256, 0, stream>>>(low, cur, high, oct, out + (size_t)7 * K, cand, cnt, cap);

    for (int pass = 0; pass < 4; ++pass) {
        hist_kernel<<<64, 256, 0, stream>>>(cand, cnt, hist, cap, pass);
        pick_kernel<<<1, 256, 0, stream>>>(cnt, hist, pass, K);
    }
    compact_kernel<<<64, 256, 0, stream>>>(cand, SG, cnt, cap);
    rank_finalize_kernel<<<SG_CAP / 256, 256, 0, stream>>>(SG, cnt, low, cur, high, aff, out, K);
}

// Round 3
// 282.339 us; speedup vs baseline: 4.2475x; 1.3034x over previous
//
#include <hip/hip_runtime.h>
#include <cstdint>
#include <cstddef>

#define HH 2048
#define WW 2048
#define NPIX (HH * WW)
#define EPS_NMS 1e-5f
#define EPS_DIV 1e-8f
#define NEG_INF (-3.402823466e+38f)
#define ROWS 8          // rows per block in nms kernel (block covers 1024 cols x ROWS rows)
#define LCAP 2048       // per-block LDS candidate capacity (expected ~300)
#define SG_CAP 8192     // max selected (>=T) keys
#define HIST_BLOCKS 64

typedef unsigned long long u64;

// ---- workspace layout (bytes) ----
// [0,    64)   : uint32 cnt[16]  cnt[0]=n_cand cnt[1]=n_sel cnt[3]=prefix/T cnt[4]=remk cnt[8..11]=done ctr per pass
// [64,  1088)  : uint32 hist[256]
// [4096,69632) : SG u64[8192]  (all keys >= T, unsorted)
// [69632, ...) : candidates u64[cap]

__device__ __forceinline__ float max3(float a, float b, float c) {
    return fmaxf(a, fmaxf(b, c));
}

// Each block: 256 threads x 4 cols = 1024 columns, ROWS rows. No per-row syncs:
// each thread loads its own 6-column z-neighborhood (float4 + 2 edge scalars).
__global__ __launch_bounds__(256) void nms_map_kernel(
    const float* __restrict__ low, const float* __restrict__ cur,
    const float* __restrict__ high, const float* __restrict__ oct,
    float* __restrict__ oct_out, u64* __restrict__ cand,
    unsigned int* __restrict__ cnt, unsigned int cap)
{
    __shared__ unsigned int lcount, lbase;
    __shared__ u64 lcand[LCAP];

    const int tid = threadIdx.x;
    const int x4 = blockIdx.x * 1024 + tid * 4;
    const int y0 = blockIdx.y * ROWS;
    if (tid == 0) lcount = 0u;
    __syncthreads();

    float4 r0, r1, c1;

    auto row_hmax = [&](int t, float4& hz, float4& cz) {
        if (t < 0 || t >= HH) {
            hz = make_float4(NEG_INF, NEG_INF, NEG_INF, NEG_INF);
            cz = make_float4(0.f, 0.f, 0.f, 0.f);
            return;
        }
        int jj = t * WW + x4;
        float4 l = *(const float4*)(low + jj);
        float4 c = *(const float4*)(cur + jj);
        float4 h = *(const float4*)(high + jj);
        cz = c;
        float zx = max3(l.x, c.x, h.x);
        float zy = max3(l.y, c.y, h.y);
        float zz = max3(l.z, c.z, h.z);
        float zw = max3(l.w, c.w, h.w);
        float zl = NEG_INF, zr = NEG_INF;
        if (x4 > 0)            zl = max3(low[jj - 1], cur[jj - 1], high[jj - 1]);
        if (x4 + 4 < WW)       zr = max3(low[jj + 4], cur[jj + 4], high[jj + 4]);
        hz.x = max3(zl, zx, zy);
        hz.y = max3(zx, zy, zz);
        hz.z = max3(zy, zz, zw);
        hz.w = max3(zz, zw, zr);
    };

    float4 cdum;
    row_hmax(y0 - 1, r0, cdum);
    row_hmax(y0,     r1, c1);

    for (int j = 0; j < ROWS; ++j) {
        int y = y0 + j;
        float4 r2, c2;
        row_hmax(y + 1, r2, c2);
        int idx = y * WW + x4;
        float4 o = *(const float4*)(oct + idx);
        bool yin = (y > 0) && (y < HH - 1);
        float4 ov;
        #define DO_COMP(comp, i)  {                                               \
            float m = max3(r0.comp, r1.comp, r2.comp);                            \
            int xg = x4 + (i);                                                    \
            bool interior = yin && (xg > 0) && (xg < WW - 1);                     \
            float nm = (((c1.comp - m + EPS_NMS) > 0.0f) && interior)             \
                       ? c1.comp * (1.0f - o.comp) : 0.0f;                        \
            ov.comp = (float)((unsigned char)(o.comp + nm));                      \
            if (nm > 0.0f) {                                                      \
                unsigned int p = atomicAdd(&lcount, 1u);                          \
                if (p < LCAP)                                                     \
                    lcand[p] = (((u64)__float_as_uint(nm)) << 32)                 \
                               | (unsigned int)(~(idx + (i)));                    \
            }                                                                     \
        }
        DO_COMP(x, 0) DO_COMP(y, 1) DO_COMP(z, 2) DO_COMP(w, 3)
        #undef DO_COMP
        *(float4*)(oct_out + idx) = ov;
        r0 = r1; r1 = r2; c1 = c2;
    }

    __syncthreads();
    unsigned int c = lcount < LCAP ? lcount : LCAP;
    if (tid == 0) lbase = atomicAdd(cnt, c);
    __syncthreads();
    unsigned int base = lbase;
    for (unsigned int i = tid; i < c; i += 256) {
        unsigned int p = base + i;
        if (p < cap) cand[p] = lcand[i];
    }
}

// one fused 8-bit radix pass: per-block LDS hist -> global hist; last block picks
__global__ __launch_bounds__(256) void hist_pick_kernel(
    const u64* __restrict__ cand, unsigned int* __restrict__ cnt,
    unsigned int* __restrict__ hist, unsigned int cap, int pass, int K)
{
    __shared__ unsigned int h[256];
    __shared__ bool amLast;
    int tid = threadIdx.x;
    h[tid] = 0u;
    __syncthreads();
    unsigned int n = cnt[0]; if (n > cap) n = cap;
    unsigned int prefix = cnt[3];
    int shift = 24 - 8 * pass;
    unsigned int stride = gridDim.x * blockDim.x;
    for (unsigned int i = blockIdx.x * blockDim.x + tid; i < n; i += stride) {
        unsigned int k32 = (unsigned int)(cand[i] >> 32);
        bool ok = (pass == 0) || ((k32 >> (shift + 8)) == prefix);
        if (ok) atomicAdd(&h[(k32 >> shift) & 255u], 1u);
    }
    __syncthreads();
    if (h[tid]) atomicAdd(&hist[tid], h[tid]);
    __threadfence();
    if (tid == 0) amLast = (atomicAdd(&cnt[8 + pass], 1u) == (unsigned int)(gridDim.x - 1));
    __syncthreads();
    if (!amLast) return;
    __threadfence();

    // pick: suffix scan over global hist (all contributions visible now)
    unsigned int hv = hist[tid];
    h[tid] = hv;
    __syncthreads();
    for (int off = 1; off < 256; off <<= 1) {
        unsigned int v = (tid + off < 256) ? h[tid + off] : 0u;
        __syncthreads();
        h[tid] += v;
        __syncthreads();
    }
    unsigned int remk = (pass == 0) ? (unsigned int)K : cnt[4];
    unsigned int incl = h[tid];
    unsigned int excl = incl - hv;
    unsigned int total = h[0];
    if (incl >= remk && excl < remk) {        // unique crossing bin (needs hv>0)
        cnt[3] = (prefix << 8) | (unsigned int)tid;
        cnt[4] = remk - excl;
    }
    if (tid == 0 && total < remk)             // degenerate: fewer than K candidates
        cnt[3] = prefix << 8;
    hist[tid] = 0u;                           // reset for next pass
}

// compact all keys with k32 >= T into SG (one global atomic per block)
__global__ __launch_bounds__(256) void compact_kernel(
    const u64* __restrict__ cand, u64* __restrict__ SG,
    unsigned int* __restrict__ cnt, unsigned int cap)
{
    __shared__ unsigned int lc, lb;
    __shared__ u64 buf[2048];
    int tid = threadIdx.x;
    unsigned int n = cnt[0]; if (n > cap) n = cap;
    unsigned int T = cnt[3];
    if (tid == 0) lc = 0u;
    __syncthreads();
    unsigned int stride = gridDim.x * blockDim.x;
    for (unsigned int i = blockIdx.x * blockDim.x + tid; i < n; i += stride) {
        u64 key = cand[i];
        if ((unsigned int)(key >> 32) >= T) {
            unsigned int p = atomicAdd(&lc, 1u);
            if (p < 2048u) buf[p] = key;
        }
    }
    __syncthreads();
    unsigned int c = lc < 2048u ? lc : 2048u;
    if (tid == 0) lb = atomicAdd(&cnt[1], c);
    __syncthreads();
    unsigned int base = lb;
    for (unsigned int i = tid; i < c; i += 256) {
        unsigned int p = base + i;
        if (p < SG_CAP) SG[p] = buf[i];
    }
}

// rank-by-count against LDS-staged keys (broadcast reads) + fused finalize
__global__ __launch_bounds__(256) void rank_finalize_kernel(
    const u64* __restrict__ SG, const unsigned int* __restrict__ cnt,
    const float* __restrict__ low, const float* __restrict__ cur,
    const float* __restrict__ high, const float* __restrict__ aff,
    float* __restrict__ out, int K)
{
    __shared__ u64 s[SG_CAP];
    unsigned int m = cnt[1]; if (m > SG_CAP) m = SG_CAP;
    for (unsigned int i = threadIdx.x; i < m; i += 256) s[i] = SG[i];
    __syncthreads();

    unsigned int e = blockIdx.x * 256 + threadIdx.x;
    if (e >= m) return;
    u64 my = s[e];
    unsigned int rank = 0, j = 0;
    for (; j + 8 <= m; j += 8) {              // uniform index -> LDS broadcast
        rank += (unsigned)(s[j]     > my) + (unsigned)(s[j + 1] > my)
              + (unsigned)(s[j + 2] > my) + (unsigned)(s[j + 3] > my)
              + (unsigned)(s[j + 4] > my) + (unsigned)(s[j + 5] > my)
              + (unsigned)(s[j + 6] > my) + (unsigned)(s[j + 7] > my);
    }
    for (; j < m; ++j) rank += (unsigned)(s[j] > my);
    if (rank >= (unsigned int)K) return;

    float val = __uint_as_float((unsigned int)(my >> 32));
    unsigned int idx = ~((unsigned int)my);
    out[rank] = val;
    float* laf = out + K + (size_t)rank * 6;
    int y = (int)(idx >> 11), x = (int)(idx & (WW - 1));
    const float ccw[3] = {-0.5f, 0.5f, 1.5f};
    float den = 0.0f, nz = 0.0f, ny = 0.0f, nx = 0.0f;
    #pragma unroll
    for (int dy = -1; dy <= 1; ++dy) {
        int yy = y + dy;
        if (yy < 0 || yy >= HH) continue;
        #pragma unroll
        for (int dx = -1; dx <= 1; ++dx) {
            int xx = x + dx;
            if (xx < 0 || xx >= WW) continue;
            int jj = yy * WW + xx;
            float v0 = low[jj], v1 = cur[jj], v2 = high[jj];
            float ssum = v0 + v1 + v2;
            den += ssum;
            nz += -0.5f * v0 + 0.5f * v1 + 1.5f * v2;
            ny += ccw[dy + 1] * ssum;
            nx += ccw[dx + 1] * ssum;
        }
    }
    float inv = 1.0f / (den + EPS_DIV);
    float s_n = (nz * inv) * (1.0f / 2048.0f);
    float y_n = (ny * inv + (float)y) * (1.0f / 2048.0f);
    float x_n = (nx * inv + (float)x) * (1.0f / 2048.0f);
    float a0 = aff[idx], a1 = aff[NPIX + idx], a2 = aff[2 * NPIX + idx], a3 = aff[3 * NPIX + idx];
    laf[0] = s_n * a0; laf[1] = s_n * a1; laf[2] = x_n;
    laf[3] = s_n * a2; laf[4] = s_n * a3; laf[5] = y_n;
}

extern "C" void kernel_launch(void* const* d_in, const int* in_sizes, int n_in,
                              void* d_out, int out_size, void* d_ws, size_t ws_size,
                              hipStream_t stream) {
    const float* low  = (const float*)d_in[0];
    const float* cur  = (const float*)d_in[1];
    const float* high = (const float*)d_in[2];
    const float* aff  = (const float*)d_in[3];
    const float* oct  = (const float*)d_in[4];
    int K = (out_size - NPIX) / 7;   // 4096
    float* out = (float*)d_out;

    char* ws = (char*)d_ws;
    unsigned int* cnt  = (unsigned int*)ws;
    unsigned int* hist = (unsigned int*)(ws + 64);
    u64* SG            = (u64*)(ws + 4096);
    const size_t cand_off = 69632;
    u64* cand          = (u64*)(ws + cand_off);
    size_t cap_sz = ws_size > cand_off ? (ws_size - cand_off) / 8 : 0;
    if (cap_sz > (size_t)NPIX) cap_sz = (size_t)NPIX;
    unsigned int cap = (unsigned int)cap_sz;

    hipMemsetAsync(ws, 0, 1088, stream);                            // cnt + hist
    hipMemsetAsync(out, 0, (size_t)7 * K * sizeof(float), stream);  // vals+lafs safety

    dim3 gb(WW / 1024, HH / ROWS, 1);
    nms_map_kernel<<<gb, 256, 0, stream>>>(low, cur, high, oct, out + (size_t)7 * K, cand, cnt, cap);

    for (int pass = 0; pass < 4; ++pass)
        hist_pick_kernel<<<HIST_BLOCKS, 256, 0, stream>>>(cand, cnt, hist, cap, pass, K);
    compact_kernel<<<64, 256, 0, stream>>>(cand, SG, cnt, cap);
    rank_finalize_kernel<<<SG_CAP / 256, 256, 0, stream>>>(SG, cnt, low, cur, high, aff, out, K);
}

// Round 4
// 231.472 us; speedup vs baseline: 5.1809x; 1.2198x over previous
//
#include <hip/hip_runtime.h>
#include <cstdint>
#include <cstddef>

#define HH 2048
#define WW 2048
#define NPIX (HH * WW)
#define EPS_NMS 1e-5f
#define EPS_DIV 1e-8f
#define NEG_INF (-3.402823466e+38f)
#define ROWS 8          // rows per block in nms kernel (block covers 1024 cols x ROWS rows)
#define LCAP 2048       // per-block LDS candidate capacity (expected ~300)
#define SG_CAP 8192     // max selected (>=T) keys
#define HIST_BLOCKS 64

typedef unsigned long long u64;

// ---- workspace layout (bytes) ----
// [0,    64)   : uint32 cnt[16]  cnt[0]=n_cand cnt[1]=n_sel cnt[3]=prefix/T cnt[4]=remk cnt[8..11]=done ctr per pass
// [64,  1088)  : uint32 hist[256]
// [4096,69632) : SG u64[8192]  (all keys >= T, unsorted)
// [69632, ...) : candidates u64[cap]

__device__ __forceinline__ float max3(float a, float b, float c) {
    return fmaxf(a, fmaxf(b, c));
}

// Each block: 256 threads x 4 cols = 1024 columns, ROWS rows. No per-row syncs:
// each thread loads its own 6-column z-neighborhood (float4 + 2 edge scalars).
__global__ __launch_bounds__(256) void nms_map_kernel(
    const float* __restrict__ low, const float* __restrict__ cur,
    const float* __restrict__ high, const float* __restrict__ oct,
    float* __restrict__ oct_out, u64* __restrict__ cand,
    unsigned int* __restrict__ cnt, unsigned int cap)
{
    __shared__ unsigned int lcount, lbase;
    __shared__ u64 lcand[LCAP];

    const int tid = threadIdx.x;
    const int x4 = blockIdx.x * 1024 + tid * 4;
    const int y0 = blockIdx.y * ROWS;
    if (tid == 0) lcount = 0u;
    __syncthreads();

    float4 r0, r1, c1;

    auto row_hmax = [&](int t, float4& hz, float4& cz) {
        if (t < 0 || t >= HH) {
            hz = make_float4(NEG_INF, NEG_INF, NEG_INF, NEG_INF);
            cz = make_float4(0.f, 0.f, 0.f, 0.f);
            return;
        }
        int jj = t * WW + x4;
        float4 l = *(const float4*)(low + jj);
        float4 c = *(const float4*)(cur + jj);
        float4 h = *(const float4*)(high + jj);
        cz = c;
        float zx = max3(l.x, c.x, h.x);
        float zy = max3(l.y, c.y, h.y);
        float zz = max3(l.z, c.z, h.z);
        float zw = max3(l.w, c.w, h.w);
        float zl = NEG_INF, zr = NEG_INF;
        if (x4 > 0)            zl = max3(low[jj - 1], cur[jj - 1], high[jj - 1]);
        if (x4 + 4 < WW)       zr = max3(low[jj + 4], cur[jj + 4], high[jj + 4]);
        hz.x = max3(zl, zx, zy);
        hz.y = max3(zx, zy, zz);
        hz.z = max3(zy, zz, zw);
        hz.w = max3(zz, zw, zr);
    };

    float4 cdum;
    row_hmax(y0 - 1, r0, cdum);
    row_hmax(y0,     r1, c1);

    for (int j = 0; j < ROWS; ++j) {
        int y = y0 + j;
        float4 r2, c2;
        row_hmax(y + 1, r2, c2);
        int idx = y * WW + x4;
        float4 o = *(const float4*)(oct + idx);
        bool yin = (y > 0) && (y < HH - 1);
        float4 ov;
        #define DO_COMP(comp, i)  {                                               \
            float m = max3(r0.comp, r1.comp, r2.comp);                            \
            int xg = x4 + (i);                                                    \
            bool interior = yin && (xg > 0) && (xg < WW - 1);                     \
            float nm = (((c1.comp - m + EPS_NMS) > 0.0f) && interior)             \
                       ? c1.comp * (1.0f - o.comp) : 0.0f;                        \
            ov.comp = (float)((unsigned char)(o.comp + nm));                      \
            if (nm > 0.0f) {                                                      \
                unsigned int p = atomicAdd(&lcount, 1u);                          \
                if (p < LCAP)                                                     \
                    lcand[p] = (((u64)__float_as_uint(nm)) << 32)                 \
                               | (unsigned int)(~(idx + (i)));                    \
            }                                                                     \
        }
        DO_COMP(x, 0) DO_COMP(y, 1) DO_COMP(z, 2) DO_COMP(w, 3)
        #undef DO_COMP
        *(float4*)(oct_out + idx) = ov;
        r0 = r1; r1 = r2; c1 = c2;
    }

    __syncthreads();
    unsigned int c = lcount < LCAP ? lcount : LCAP;
    if (tid == 0) lbase = atomicAdd(cnt, c);
    __syncthreads();
    unsigned int base = lbase;
    for (unsigned int i = tid; i < c; i += 256) {
        unsigned int p = base + i;
        if (p < cap) cand[p] = lcand[i];
    }
}

// one fused 8-bit radix pass: per-block LDS hist -> global hist; last block picks
__global__ __launch_bounds__(256) void hist_pick_kernel(
    const u64* __restrict__ cand, unsigned int* __restrict__ cnt,
    unsigned int* __restrict__ hist, unsigned int cap, int pass, int K)
{
    __shared__ unsigned int h[256];
    __shared__ bool amLast;
    int tid = threadIdx.x;
    h[tid] = 0u;
    __syncthreads();
    unsigned int n = cnt[0]; if (n > cap) n = cap;
    unsigned int prefix = cnt[3];
    int shift = 24 - 8 * pass;
    unsigned int stride = gridDim.x * blockDim.x;
    for (unsigned int i = blockIdx.x * blockDim.x + tid; i < n; i += stride) {
        unsigned int k32 = (unsigned int)(cand[i] >> 32);
        bool ok = (pass == 0) || ((k32 >> (shift + 8)) == prefix);
        if (ok) atomicAdd(&h[(k32 >> shift) & 255u], 1u);
    }
    __syncthreads();
    if (h[tid]) atomicAdd(&hist[tid], h[tid]);
    __threadfence();
    if (tid == 0) amLast = (atomicAdd(&cnt[8 + pass], 1u) == (unsigned int)(gridDim.x - 1));
    __syncthreads();
    if (!amLast) return;
    __threadfence();

    // pick: suffix scan over global hist (all contributions visible now)
    unsigned int hv = hist[tid];
    h[tid] = hv;
    __syncthreads();
    for (int off = 1; off < 256; off <<= 1) {
        unsigned int v = (tid + off < 256) ? h[tid + off] : 0u;
        __syncthreads();
        h[tid] += v;
        __syncthreads();
    }
    unsigned int remk = (pass == 0) ? (unsigned int)K : cnt[4];
    unsigned int incl = h[tid];
    unsigned int excl = incl - hv;
    unsigned int total = h[0];
    if (incl >= remk && excl < remk) {        // unique crossing bin (needs hv>0)
        cnt[3] = (prefix << 8) | (unsigned int)tid;
        cnt[4] = remk - excl;
    }
    if (tid == 0 && total < remk)             // degenerate: fewer than K candidates
        cnt[3] = prefix << 8;
    hist[tid] = 0u;                           // reset for next pass
}

// compact all keys with k32 >= T into SG (one global atomic per block)
__global__ __launch_bounds__(256) void compact_kernel(
    const u64* __restrict__ cand, u64* __restrict__ SG,
    unsigned int* __restrict__ cnt, unsigned int cap)
{
    __shared__ unsigned int lc, lb;
    __shared__ u64 buf[2048];
    int tid = threadIdx.x;
    unsigned int n = cnt[0]; if (n > cap) n = cap;
    unsigned int T = cnt[3];
    if (tid == 0) lc = 0u;
    __syncthreads();
    unsigned int stride = gridDim.x * blockDim.x;
    for (unsigned int i = blockIdx.x * blockDim.x + tid; i < n; i += stride) {
        u64 key = cand[i];
        if ((unsigned int)(key >> 32) >= T) {
            unsigned int p = atomicAdd(&lc, 1u);
            if (p < 2048u) buf[p] = key;
        }
    }
    __syncthreads();
    unsigned int c = lc < 2048u ? lc : 2048u;
    if (tid == 0) lb = atomicAdd(&cnt[1], c);
    __syncthreads();
    unsigned int base = lb;
    for (unsigned int i = tid; i < c; i += 256) {
        unsigned int p = base + i;
        if (p < SG_CAP) SG[p] = buf[i];
    }
}

// one WAVE per element: lanes partial-count rank over coalesced L2-resident SG,
// shfl-reduce, lane 0 does the centroid fit + LAF write.
__global__ __launch_bounds__(256) void rank_finalize_kernel(
    const u64* __restrict__ SG, const unsigned int* __restrict__ cnt,
    const float* __restrict__ low, const float* __restrict__ cur,
    const float* __restrict__ high, const float* __restrict__ aff,
    float* __restrict__ out, int K)
{
    unsigned int m = cnt[1]; if (m > SG_CAP) m = SG_CAP;
    unsigned int wave = threadIdx.x >> 6;
    unsigned int lane = threadIdx.x & 63u;
    unsigned int e = blockIdx.x * 4 + wave;
    if (e >= m) return;
    u64 my = SG[e];

    unsigned int rank = 0;
    for (unsigned int j = lane; j < m; j += 64)   // coalesced; SG is L2-resident
        rank += (unsigned)(SG[j] > my);
    #pragma unroll
    for (int off = 32; off > 0; off >>= 1)
        rank += __shfl_down(rank, off, 64);
    if (lane != 0) return;
    if (rank >= (unsigned int)K) return;

    float val = __uint_as_float((unsigned int)(my >> 32));
    unsigned int idx = ~((unsigned int)my);
    out[rank] = val;
    float* laf = out + K + (size_t)rank * 6;
    int y = (int)(idx >> 11), x = (int)(idx & (WW - 1));
    const float ccw[3] = {-0.5f, 0.5f, 1.5f};
    float den = 0.0f, nz = 0.0f, ny = 0.0f, nx = 0.0f;
    #pragma unroll
    for (int dy = -1; dy <= 1; ++dy) {
        int yy = y + dy;
        if (yy < 0 || yy >= HH) continue;
        #pragma unroll
        for (int dx = -1; dx <= 1; ++dx) {
            int xx = x + dx;
            if (xx < 0 || xx >= WW) continue;
            int jj = yy * WW + xx;
            float v0 = low[jj], v1 = cur[jj], v2 = high[jj];
            float ssum = v0 + v1 + v2;
            den += ssum;
            nz += -0.5f * v0 + 0.5f * v1 + 1.5f * v2;
            ny += ccw[dy + 1] * ssum;
            nx += ccw[dx + 1] * ssum;
        }
    }
    float inv = 1.0f / (den + EPS_DIV);
    float s_n = (nz * inv) * (1.0f / 2048.0f);
    float y_n = (ny * inv + (float)y) * (1.0f / 2048.0f);
    float x_n = (nx * inv + (float)x) * (1.0f / 2048.0f);
    float a0 = aff[idx], a1 = aff[NPIX + idx], a2 = aff[2 * NPIX + idx], a3 = aff[3 * NPIX + idx];
    laf[0] = s_n * a0; laf[1] = s_n * a1; laf[2] = x_n;
    laf[3] = s_n * a2; laf[4] = s_n * a3; laf[5] = y_n;
}

extern "C" void kernel_launch(void* const* d_in, const int* in_sizes, int n_in,
                              void* d_out, int out_size, void* d_ws, size_t ws_size,
                              hipStream_t stream) {
    const float* low  = (const float*)d_in[0];
    const float* cur  = (const float*)d_in[1];
    const float* high = (const float*)d_in[2];
    const float* aff  = (const float*)d_in[3];
    const float* oct  = (const float*)d_in[4];
    int K = (out_size - NPIX) / 7;   // 4096
    float* out = (float*)d_out;

    char* ws = (char*)d_ws;
    unsigned int* cnt  = (unsigned int*)ws;
    unsigned int* hist = (unsigned int*)(ws + 64);
    u64* SG            = (u64*)(ws + 4096);
    const size_t cand_off = 69632;
    u64* cand          = (u64*)(ws + cand_off);
    size_t cap_sz = ws_size > cand_off ? (ws_size - cand_off) / 8 : 0;
    if (cap_sz > (size_t)NPIX) cap_sz = (size_t)NPIX;
    unsigned int cap = (unsigned int)cap_sz;

    hipMemsetAsync(ws, 0, 1088, stream);                            // cnt + hist
    hipMemsetAsync(out, 0, (size_t)7 * K * sizeof(float), stream);  // vals+lafs safety

    dim3 gb(WW / 1024, HH / ROWS, 1);
    nms_map_kernel<<<gb, 256, 0, stream>>>(low, cur, high, oct, out + (size_t)7 * K, cand, cnt, cap);

    for (int pass = 0; pass < 4; ++pass)
        hist_pick_kernel<<<HIST_BLOCKS, 256, 0, stream>>>(cand, cnt, hist, cap, pass, K);
    compact_kernel<<<64, 256, 0, stream>>>(cand, SG, cnt, cap);
    rank_finalize_kernel<<<SG_CAP / 4, 256, 0, stream>>>(SG, cnt, low, cur, high, aff, out, K);
}

// Round 5
// 211.633 us; speedup vs baseline: 5.6666x; 1.0937x over previous
//
#include <hip/hip_runtime.h>
#include <cstdint>
#include <cstddef>

#define HH 2048
#define WW 2048
#define NPIX (HH * WW)
#define EPS_NMS 1e-5f
#define EPS_DIV 1e-8f
#define NEG_INF (-3.402823466e+38f)
#define ROWS 4          // rows per block (block covers 1024 cols x ROWS rows)
#define LCAP 1024       // per-block candidate cap; provably >= max density (1 per 2x2)
#define SG_CAP 8192     // max selected (>=T22) keys
#define NBIN 2048       // 11-bit radix bins
#define HIST_BLOCKS 64

typedef unsigned long long u64;

// ---- workspace layout (bytes) ----
// [0,    64)    : uint32 cnt[16]  0=n_cand 1=n_sel 3=prefix/T22 4=remk 8/9=arrive ctr
// [64,  8256)   : uint32 hist[2048]
// [16384,81920) : SG u64[8192]  (all keys with top22 >= T22, unsorted)
// [81920, ...)  : candidates u64[cap]

__device__ __forceinline__ float max3(float a, float b, float c) {
    return fmaxf(a, fmaxf(b, c));
}

// Block: 256 threads x 4 cols = 1024 cols, ROWS rows. ALL tile loads issued
// up front into register arrays (MLP); horizontal halo via wave shfl, only
// lanes 0/63 load edge scalars.
__global__ __launch_bounds__(256) void nms_map_kernel(
    const float* __restrict__ low, const float* __restrict__ cur,
    const float* __restrict__ high, const float* __restrict__ oct,
    float* __restrict__ oct_out, u64* __restrict__ cand,
    unsigned int* __restrict__ cnt, unsigned int cap)
{
    __shared__ unsigned int lcount, lbase;
    __shared__ u64 lcand[LCAP];

    const int tid = threadIdx.x;
    const int lane = tid & 63;
    const int x4 = blockIdx.x * 1024 + tid * 4;
    const int y0 = blockIdx.y * ROWS;
    if (tid == 0) lcount = 0u;
    __syncthreads();

    // ---- phase 1: issue ALL z-cube loads (6 rows x 3 arrays) up front ----
    float4 L[ROWS + 2], C[ROWS + 2], Hi[ROWS + 2];
    float eL[ROWS + 2][3], eR[ROWS + 2][3];
    #pragma unroll
    for (int r = 0; r < ROWS + 2; ++r) {
        int t = y0 - 1 + r;
        bool valid = (t >= 0) && (t < HH);
        int jj = valid ? (t * WW + x4) : 0;
        if (valid) {
            L[r]  = *(const float4*)(low + jj);
            C[r]  = *(const float4*)(cur + jj);
            Hi[r] = *(const float4*)(high + jj);
        } else {
            L[r] = C[r] = Hi[r] = make_float4(NEG_INF, NEG_INF, NEG_INF, NEG_INF);
        }
        bool doL = valid && (lane == 0) && (x4 > 0);
        bool doR = valid && (lane == 63) && (x4 + 4 < WW);
        eL[r][0] = doL ? low[jj - 1]  : NEG_INF;
        eL[r][1] = doL ? cur[jj - 1]  : NEG_INF;
        eL[r][2] = doL ? high[jj - 1] : NEG_INF;
        eR[r][0] = doR ? low[jj + 4]  : NEG_INF;
        eR[r][1] = doR ? cur[jj + 4]  : NEG_INF;
        eR[r][2] = doR ? high[jj + 4] : NEG_INF;
    }
    float4 O[ROWS];
    #pragma unroll
    for (int j = 0; j < ROWS; ++j)
        O[j] = *(const float4*)(oct + (y0 + j) * WW + x4);

    // ---- phase 2: horizontal 3-window max of z-max per row ----
    float4 hz[ROWS + 2], cv[ROWS + 2];
    #pragma unroll
    for (int r = 0; r < ROWS + 2; ++r) {
        int t = y0 - 1 + r;
        bool valid = (t >= 0) && (t < HH);
        float4 z;
        z.x = max3(L[r].x, C[r].x, Hi[r].x);
        z.y = max3(L[r].y, C[r].y, Hi[r].y);
        z.z = max3(L[r].z, C[r].z, Hi[r].z);
        z.w = max3(L[r].w, C[r].w, Hi[r].w);
        float zeL = max3(eL[r][0], eL[r][1], eL[r][2]);
        float zeR = max3(eR[r][0], eR[r][1], eR[r][2]);
        float zl = __shfl_up(z.w, 1, 64);
        float zr = __shfl_down(z.x, 1, 64);
        if (lane == 0)  zl = zeL;
        if (lane == 63) zr = zeR;
        if (valid) {
            hz[r].x = max3(zl,  z.x, z.y);
            hz[r].y = max3(z.x, z.y, z.z);
            hz[r].z = max3(z.y, z.z, z.w);
            hz[r].w = max3(z.z, z.w, zr);
            cv[r] = C[r];
        } else {
            hz[r] = make_float4(NEG_INF, NEG_INF, NEG_INF, NEG_INF);
            cv[r] = make_float4(0.f, 0.f, 0.f, 0.f);
        }
    }

    // ---- phase 3: NMS + octave update + candidate push ----
    #pragma unroll
    for (int j = 0; j < ROWS; ++j) {
        int y = y0 + j;
        int idx = y * WW + x4;
        float4 o = O[j];
        float4 c1 = cv[j + 1];
        bool yin = (y > 0) && (y < HH - 1);
        float4 ov;
        #define DO_COMP(comp, i)  {                                               \
            float m = max3(hz[j].comp, hz[j + 1].comp, hz[j + 2].comp);           \
            int xg = x4 + (i);                                                    \
            bool interior = yin && (xg > 0) && (xg < WW - 1);                     \
            float nm = (((c1.comp - m + EPS_NMS) > 0.0f) && interior)             \
                       ? c1.comp * (1.0f - o.comp) : 0.0f;                        \
            ov.comp = (float)((unsigned char)(o.comp + nm));                      \
            if (nm > 0.0f) {                                                      \
                unsigned int p = atomicAdd(&lcount, 1u);                          \
                if (p < LCAP)                                                     \
                    lcand[p] = (((u64)__float_as_uint(nm)) << 32)                 \
                               | (unsigned int)(~(idx + (i)));                    \
            }                                                                     \
        }
        DO_COMP(x, 0) DO_COMP(y, 1) DO_COMP(z, 2) DO_COMP(w, 3)
        #undef DO_COMP
        *(float4*)(oct_out + idx) = ov;
    }

    __syncthreads();
    unsigned int c = lcount < LCAP ? lcount : LCAP;
    if (tid == 0) lbase = atomicAdd(cnt, c);
    __syncthreads();
    unsigned int base = lbase;
    for (unsigned int i = tid; i < c; i += 256) {
        unsigned int p = base + i;
        if (p < cap) cand[p] = lcand[i];
    }
}

// one 11-bit radix pass: per-block LDS hist (absorbs skew) -> global hist;
// last-done block does the two-level suffix-scan pick.
__global__ __launch_bounds__(256) void hist_pick_kernel(
    const u64* __restrict__ cand, unsigned int* __restrict__ cnt,
    unsigned int* __restrict__ hist, unsigned int cap, int pass, int K)
{
    __shared__ unsigned int h[NBIN];
    __shared__ unsigned int s[256];
    __shared__ bool amLast;
    int tid = threadIdx.x;
    for (int i = tid; i < NBIN; i += 256) h[i] = 0u;
    __syncthreads();
    unsigned int n = cnt[0]; if (n > cap) n = cap;
    unsigned int prefix = cnt[3];
    unsigned int stride = gridDim.x * blockDim.x;
    for (unsigned int i = blockIdx.x * blockDim.x + tid; i < n; i += stride) {
        unsigned int k32 = (unsigned int)(cand[i] >> 32);
        if (pass == 0) {
            atomicAdd(&h[k32 >> 21], 1u);
        } else if ((k32 >> 21) == prefix) {
            atomicAdd(&h[(k32 >> 10) & (NBIN - 1u)], 1u);
        }
    }
    __syncthreads();
    for (int i = tid; i < NBIN; i += 256) { unsigned int v = h[i]; if (v) atomicAdd(&hist[i], v); }
    __threadfence();
    if (tid == 0) amLast = (atomicAdd(&cnt[8 + pass], 1u) == gridDim.x - 1u);
    __syncthreads();
    if (!amLast) return;
    __threadfence();

    // pick: thread t owns bins [t*8, t*8+8)
    unsigned int bins[8], csum = 0;
    #pragma unroll
    for (int i = 0; i < 8; ++i) { bins[i] = hist[tid * 8 + i]; csum += bins[i]; }
    s[tid] = csum;
    __syncthreads();
    for (int off = 1; off < 256; off <<= 1) {
        unsigned int v = (tid + off < 256) ? s[tid + off] : 0u;
        __syncthreads();
        s[tid] += v;
        __syncthreads();
    }
    unsigned int remk = (pass == 0) ? (unsigned int)K : cnt[4];
    unsigned int incl = s[tid];
    unsigned int excl = incl - csum;
    unsigned int total = s[0];
    if (incl >= remk && excl < remk) {      // unique crossing chunk
        unsigned int cum = excl;
        int b = 7;
        for (; b > 0; --b) { cum += bins[b]; if (cum >= remk) break; }
        if (cum < remk) cum += bins[0];     // b==0 fallthrough
        cnt[3] = (prefix << 11) | (unsigned int)(tid * 8 + b);
        cnt[4] = remk - (cum - bins[b]);
    }
    if (tid == 0 && total < remk)           // degenerate: fewer than K candidates
        cnt[3] = (prefix << 11);
    for (int i = tid; i < NBIN; i += 256) hist[i] = 0u;   // reset for next pass
}

// compact all keys with top22 >= T22 into SG (one global atomic per block)
__global__ __launch_bounds__(256) void compact_kernel(
    const u64* __restrict__ cand, u64* __restrict__ SG,
    unsigned int* __restrict__ cnt, unsigned int cap)
{
    __shared__ unsigned int lc, lb;
    __shared__ u64 buf[2048];
    int tid = threadIdx.x;
    unsigned int n = cnt[0]; if (n > cap) n = cap;
    unsigned int T = cnt[3];
    if (tid == 0) lc = 0u;
    __syncthreads();
    unsigned int stride = gridDim.x * blockDim.x;
    for (unsigned int i = blockIdx.x * blockDim.x + tid; i < n; i += stride) {
        u64 key = cand[i];
        if (((unsigned int)(key >> 32) >> 10) >= T) {
            unsigned int p = atomicAdd(&lc, 1u);
            if (p < 2048u) buf[p] = key;
        }
    }
    __syncthreads();
    unsigned int c = lc < 2048u ? lc : 2048u;
    if (tid == 0) lb = atomicAdd(&cnt[1], c);
    __syncthreads();
    unsigned int base = lb;
    for (unsigned int i = tid; i < c; i += 256) {
        unsigned int p = base + i;
        if (p < SG_CAP) SG[p] = buf[i];
    }
}

// one WAVE per element: lanes partial-count exact 64-bit rank over coalesced
// L2-resident SG, shfl-reduce, lane 0 does the centroid fit + LAF write.
__global__ __launch_bounds__(256) void rank_finalize_kernel(
    const u64* __restrict__ SG, const unsigned int* __restrict__ cnt,
    const float* __restrict__ low, const float* __restrict__ cur,
    const float* __restrict__ high, const float* __restrict__ aff,
    float* __restrict__ out, int K)
{
    unsigned int m = cnt[1]; if (m > SG_CAP) m = SG_CAP;
    unsigned int wave = threadIdx.x >> 6;
    unsigned int lane = threadIdx.x & 63u;
    unsigned int e = blockIdx.x * 4 + wave;
    if (e >= m) return;
    u64 my = SG[e];

    unsigned int rank = 0;
    for (unsigned int j = lane; j < m; j += 64)
        rank += (unsigned)(SG[j] > my);
    #pragma unroll
    for (int off = 32; off > 0; off >>= 1)
        rank += __shfl_down(rank, off, 64);
    if (lane != 0) return;
    if (rank >= (unsigned int)K) return;

    float val = __uint_as_float((unsigned int)(my >> 32));
    unsigned int idx = ~((unsigned int)my);
    out[rank] = val;
    float* laf = out + K + (size_t)rank * 6;
    int y = (int)(idx >> 11), x = (int)(idx & (WW - 1));
    const float ccw[3] = {-0.5f, 0.5f, 1.5f};
    float den = 0.0f, nz = 0.0f, ny = 0.0f, nx = 0.0f;
    #pragma unroll
    for (int dy = -1; dy <= 1; ++dy) {
        int yy = y + dy;
        if (yy < 0 || yy >= HH) continue;
        #pragma unroll
        for (int dx = -1; dx <= 1; ++dx) {
            int xx = x + dx;
            if (xx < 0 || xx >= WW) continue;
            int jj = yy * WW + xx;
            float v0 = low[jj], v1 = cur[jj], v2 = high[jj];
            float ssum = v0 + v1 + v2;
            den += ssum;
            nz += -0.5f * v0 + 0.5f * v1 + 1.5f * v2;
            ny += ccw[dy + 1] * ssum;
            nx += ccw[dx + 1] * ssum;
        }
    }
    float inv = 1.0f / (den + EPS_DIV);
    float s_n = (nz * inv) * (1.0f / 2048.0f);
    float y_n = (ny * inv + (float)y) * (1.0f / 2048.0f);
    float x_n = (nx * inv + (float)x) * (1.0f / 2048.0f);
    float a0 = aff[idx], a1 = aff[NPIX + idx], a2 = aff[2 * NPIX + idx], a3 = aff[3 * NPIX + idx];
    laf[0] = s_n * a0; laf[1] = s_n * a1; laf[2] = x_n;
    laf[3] = s_n * a2; laf[4] = s_n * a3; laf[5] = y_n;
}

extern "C" void kernel_launch(void* const* d_in, const int* in_sizes, int n_in,
                              void* d_out, int out_size, void* d_ws, size_t ws_size,
                              hipStream_t stream) {
    const float* low  = (const float*)d_in[0];
    const float* cur  = (const float*)d_in[1];
    const float* high = (const float*)d_in[2];
    const float* aff  = (const float*)d_in[3];
    const float* oct  = (const float*)d_in[4];
    int K = (out_size - NPIX) / 7;   // 4096
    float* out = (float*)d_out;

    char* ws = (char*)d_ws;
    unsigned int* cnt  = (unsigned int*)ws;
    unsigned int* hist = (unsigned int*)(ws + 64);
    u64* SG            = (u64*)(ws + 16384);
    const size_t cand_off = 81920;
    u64* cand          = (u64*)(ws + cand_off);
    size_t cap_sz = ws_size > cand_off ? (ws_size - cand_off) / 8 : 0;
    if (cap_sz > (size_t)NPIX) cap_sz = (size_t)NPIX;
    unsigned int cap = (unsigned int)cap_sz;

    hipMemsetAsync(ws, 0, 64 + NBIN * 4, stream);                   // cnt + hist
    hipMemsetAsync(out, 0, (size_t)7 * K * sizeof(float), stream);  // vals+lafs safety

    dim3 gb(WW / 1024, HH / ROWS, 1);
    nms_map_kernel<<<gb, 256, 0, stream>>>(low, cur, high, oct, out + (size_t)7 * K, cand, cnt, cap);

    hist_pick_kernel<<<HIST_BLOCKS, 256, 0, stream>>>(cand, cnt, hist, cap, 0, K);
    hist_pick_kernel<<<HIST_BLOCKS, 256, 0, stream>>>(cand, cnt, hist, cap, 1, K);
    compact_kernel<<<64, 256, 0, stream>>>(cand, SG, cnt, cap);
    rank_finalize_kernel<<<SG_CAP / 4, 256, 0, stream>>>(SG, cnt, low, cur, high, aff, out, K);
}